// Round 1
// baseline (563.617 us; speedup 1.0000x reference)
//
#include <hip/hip_runtime.h>

#define NROWS 16384
#define HID   512
#define PROJ  128

constexpr float SCALE_L2E = 2.8853900817779268f; // log2(e)/tau, tau=0.5
constexpr float E2        = 7.38905609893065f;   // exp(1/tau) = diag(intra)

typedef float f32x4  __attribute__((ext_vector_type(4)));
typedef short bf16x8 __attribute__((ext_vector_type(8)));

__device__ inline short f2bf(float x) {
  union { float f; unsigned u; } v; v.f = x;
  unsigned r = v.u + 0x7fffu + ((v.u >> 16) & 1u); // RNE
  return (short)(r >> 16);
}
__device__ inline float bf2f(short s) {
  union { unsigned u; float f; } v; v.u = ((unsigned)(unsigned short)s) << 16;
  return v.f;
}

// ---- prep: W1 (512x128) -> W1t bf16 (128x512); W2 (128x128) -> W2t bf16 (128x128)
__global__ void kprep(const float* __restrict__ W1, const float* __restrict__ W2,
                      short* __restrict__ W1t, short* __restrict__ W2t) {
  int stride = gridDim.x * blockDim.x;
  for (int idx = blockIdx.x * blockDim.x + threadIdx.x; idx < 128 * 512; idx += stride) {
    int n = idx >> 9, k = idx & 511;
    W1t[idx] = f2bf(W1[k * 128 + n]);
  }
  for (int idx = blockIdx.x * blockDim.x + threadIdx.x; idx < 128 * 128; idx += stride) {
    int n = idx >> 7, k = idx & 127;
    W2t[idx] = f2bf(W2[k * 128 + n]);
  }
}

// ---- GEMM1: h = elu(z @ W1 + b1), z f32 [16384][512], out bf16 [16384][128]
__global__ __launch_bounds__(256) void kproj1(const float* __restrict__ z,
                                              const short* __restrict__ W1t,
                                              const float* __restrict__ b1,
                                              short* __restrict__ h) {
  int wave = threadIdx.x >> 6, lane = threadIdx.x & 63;
  int lr = lane & 15, lg = lane >> 4;
  int row0 = blockIdx.x * 64 + wave * 16;
  const float* zrow = z + (size_t)(row0 + lr) * HID;

  f32x4 acc[8];
#pragma unroll
  for (int ct = 0; ct < 8; ++ct) acc[ct] = (f32x4){0.f, 0.f, 0.f, 0.f};

  for (int kc = 0; kc < HID / 32; ++kc) {
    int kof = kc * 32 + lg * 8;
    f32x4 za = *(const f32x4*)(zrow + kof);
    f32x4 zb = *(const f32x4*)(zrow + kof + 4);
    bf16x8 a;
    a[0] = f2bf(za[0]); a[1] = f2bf(za[1]); a[2] = f2bf(za[2]); a[3] = f2bf(za[3]);
    a[4] = f2bf(zb[0]); a[5] = f2bf(zb[1]); a[6] = f2bf(zb[2]); a[7] = f2bf(zb[3]);
#pragma unroll
    for (int ct = 0; ct < 8; ++ct) {
      bf16x8 b = *(const bf16x8*)(W1t + (ct * 16 + lr) * HID + kof);
      acc[ct] = __builtin_amdgcn_mfma_f32_16x16x32_bf16(a, b, acc[ct], 0, 0, 0);
    }
  }
  // C/D: col = lane&15, row = (lane>>4)*4 + q
#pragma unroll
  for (int ct = 0; ct < 8; ++ct) {
    int col = ct * 16 + lr;
    float bias = b1[col];
#pragma unroll
    for (int q = 0; q < 4; ++q) {
      int row = row0 + lg * 4 + q;
      float x = acc[ct][q] + bias;
      x = x > 0.f ? x : expm1f(x);
      h[(size_t)row * PROJ + col] = f2bf(x);
    }
  }
}

// ---- GEMM2 + bias + L2-normalize; writes nu (bf16) and nu_scaled (bf16, * log2e/tau)
__global__ __launch_bounds__(256) void kproj2(const short* __restrict__ h,
                                              const short* __restrict__ W2t,
                                              const float* __restrict__ b2,
                                              short* __restrict__ outn,
                                              short* __restrict__ outns) {
  int wave = threadIdx.x >> 6, lane = threadIdx.x & 63;
  int lr = lane & 15, lg = lane >> 4;
  int row0 = blockIdx.x * 64 + wave * 16;
  const short* hrow = h + (size_t)(row0 + lr) * PROJ;

  f32x4 acc[8];
#pragma unroll
  for (int ct = 0; ct < 8; ++ct) acc[ct] = (f32x4){0.f, 0.f, 0.f, 0.f};

#pragma unroll
  for (int kc = 0; kc < PROJ / 32; ++kc) {
    int kof = kc * 32 + lg * 8;
    bf16x8 a = *(const bf16x8*)(hrow + kof);
#pragma unroll
    for (int ct = 0; ct < 8; ++ct) {
      bf16x8 b = *(const bf16x8*)(W2t + (ct * 16 + lr) * PROJ + kof);
      acc[ct] = __builtin_amdgcn_mfma_f32_16x16x32_bf16(a, b, acc[ct], 0, 0, 0);
    }
  }
#pragma unroll
  for (int ct = 0; ct < 8; ++ct) {
    float bias = b2[ct * 16 + lr];
#pragma unroll
    for (int q = 0; q < 4; ++q) acc[ct][q] += bias;
  }
  // row norms: row r = row0 + lg*4 + q lives on the 16 lanes sharing lg (lr=0..15), 8 ct each
  float inv[4];
#pragma unroll
  for (int q = 0; q < 4; ++q) {
    float s = 0.f;
#pragma unroll
    for (int ct = 0; ct < 8; ++ct) s += acc[ct][q] * acc[ct][q];
    s += __shfl_xor(s, 1); s += __shfl_xor(s, 2);
    s += __shfl_xor(s, 4); s += __shfl_xor(s, 8);
    inv[q] = 1.f / fmaxf(sqrtf(s), 1e-12f);
  }
#pragma unroll
  for (int ct = 0; ct < 8; ++ct) {
    int col = ct * 16 + lr;
#pragma unroll
    for (int q = 0; q < 4; ++q) {
      int row = row0 + lg * 4 + q;
      float v = acc[ct][q] * inv[q];
      outn[(size_t)row * PROJ + col]  = f2bf(v);
      outns[(size_t)row * PROJ + col] = f2bf(v * SCALE_L2E);
    }
  }
}

// ---- similarity: rowsums of exp2(A_s . B) for UU+UV -> dU, VV+VU -> dV
__global__ __launch_bounds__(256) void ksim(const short* __restrict__ nu,
                                            const short* __restrict__ nv,
                                            const short* __restrict__ nus,
                                            const short* __restrict__ nvs,
                                            float* __restrict__ dU,
                                            float* __restrict__ dV) {
  int wave = threadIdx.x >> 6, lane = threadIdx.x & 63;
  int lr = lane & 15, lg = lane >> 4;
  int ib = blockIdx.x & 127, js = blockIdx.x >> 7;
  int i0 = ib * 128 + wave * 32;

  // A-fragments register-resident for the whole kernel: 2 row-blocks x 4 k-chunks x 2 mats
  bf16x8 au[2][4], av[2][4];
#pragma unroll
  for (int rb = 0; rb < 2; ++rb)
#pragma unroll
    for (int kc = 0; kc < 4; ++kc) {
      int r = i0 + rb * 16 + lr;
      au[rb][kc] = *(const bf16x8*)(nus + (size_t)r * PROJ + kc * 32 + lg * 8);
      av[rb][kc] = *(const bf16x8*)(nvs + (size_t)r * PROJ + kc * 32 + lg * 8);
    }

  float rU[2][4], rV[2][4];
#pragma unroll
  for (int rb = 0; rb < 2; ++rb)
#pragma unroll
    for (int q = 0; q < 4; ++q) { rU[rb][q] = 0.f; rV[rb][q] = 0.f; }

  int jbeg = js * (NROWS / 4), jend = jbeg + (NROWS / 4);
  for (int j0 = jbeg; j0 < jend; j0 += 16) {
    const short* pu = nu + (size_t)(j0 + lr) * PROJ + lg * 8;
    const short* pv = nv + (size_t)(j0 + lr) * PROJ + lg * 8;
    bf16x8 bu[4], bv[4];
#pragma unroll
    for (int kc = 0; kc < 4; ++kc) {
      bu[kc] = *(const bf16x8*)(pu + kc * 32);
      bv[kc] = *(const bf16x8*)(pv + kc * 32);
    }
#pragma unroll
    for (int rb = 0; rb < 2; ++rb) {
      f32x4 cuu = (f32x4){0.f,0.f,0.f,0.f}, cuv = (f32x4){0.f,0.f,0.f,0.f};
      f32x4 cvv = (f32x4){0.f,0.f,0.f,0.f}, cvu = (f32x4){0.f,0.f,0.f,0.f};
#pragma unroll
      for (int kc = 0; kc < 4; ++kc) {
        cuu = __builtin_amdgcn_mfma_f32_16x16x32_bf16(au[rb][kc], bu[kc], cuu, 0, 0, 0);
        cuv = __builtin_amdgcn_mfma_f32_16x16x32_bf16(au[rb][kc], bv[kc], cuv, 0, 0, 0);
        cvv = __builtin_amdgcn_mfma_f32_16x16x32_bf16(av[rb][kc], bv[kc], cvv, 0, 0, 0);
        cvu = __builtin_amdgcn_mfma_f32_16x16x32_bf16(av[rb][kc], bu[kc], cvu, 0, 0, 0);
      }
#pragma unroll
      for (int q = 0; q < 4; ++q) {
        rU[rb][q] += exp2f(cuu[q]) + exp2f(cuv[q]);
        rV[rb][q] += exp2f(cvv[q]) + exp2f(cvu[q]);
      }
    }
  }
  // reduce across the 16 lanes (lr) holding the same rows, then one atomic per row
#pragma unroll
  for (int rb = 0; rb < 2; ++rb)
#pragma unroll
    for (int q = 0; q < 4; ++q) {
      float u = rU[rb][q], v = rV[rb][q];
      u += __shfl_xor(u, 1); u += __shfl_xor(u, 2); u += __shfl_xor(u, 4); u += __shfl_xor(u, 8);
      v += __shfl_xor(v, 1); v += __shfl_xor(v, 2); v += __shfl_xor(v, 4); v += __shfl_xor(v, 8);
      if (lr == 0) {
        int row = i0 + rb * 16 + lg * 4 + q;
        atomicAdd(&dU[row], u);
        atomicAdd(&dV[row], v);
      }
    }
}

// ---- final: per-row loss, mean into d_out
__global__ __launch_bounds__(256) void kfinal(const short* __restrict__ nu,
                                              const short* __restrict__ nv,
                                              const float* __restrict__ dU,
                                              const float* __restrict__ dV,
                                              float* __restrict__ out) {
  int wave = threadIdx.x >> 6, lane = threadIdx.x & 63;
  int i = blockIdx.x * 256 + threadIdx.x;

  const bf16x8* a = (const bf16x8*)(nu + (size_t)i * PROJ);
  const bf16x8* b = (const bf16x8*)(nv + (size_t)i * PROJ);
  float s = 0.f;
#pragma unroll
  for (int t = 0; t < PROJ / 8; ++t) {
    bf16x8 x = a[t], y = b[t];
#pragma unroll
    for (int e = 0; e < 8; ++e) s += bf2f(x[e]) * bf2f(y[e]);
  }
  float den1 = dU[i] - E2;
  float den2 = dV[i] - E2;
  // 0.5*(l1+l2) = 0.5*(log den1 + log den2) - s/tau
  float li = 0.5f * (logf(den1) + logf(den2)) - s * 2.0f;

#pragma unroll
  for (int m = 1; m < 64; m <<= 1) li += __shfl_xor(li, m);
  __shared__ float ws4[4];
  if (lane == 0) ws4[wave] = li;
  __syncthreads();
  if (threadIdx.x == 0)
    atomicAdd(out, (ws4[0] + ws4[1] + ws4[2] + ws4[3]) * (1.f / (float)NROWS));
}

extern "C" void kernel_launch(void* const* d_in, const int* in_sizes, int n_in,
                              void* d_out, int out_size, void* d_ws, size_t ws_size,
                              hipStream_t stream) {
  (void)in_sizes; (void)n_in; (void)out_size; (void)ws_size;
  const float* z1 = (const float*)d_in[0];
  const float* z2 = (const float*)d_in[1];
  const float* W1 = (const float*)d_in[2];
  const float* b1 = (const float*)d_in[3];
  const float* W2 = (const float*)d_in[4];
  const float* b2 = (const float*)d_in[5];
  float* out = (float*)d_out;

  short* W1t = (short*)d_ws;                      // 128*512
  short* W2t = W1t + 128 * 512;                   // 128*128
  short* hb  = W2t + 128 * 128;                   // 16384*128 (reused for z1 and z2)
  short* nu  = hb  + (size_t)NROWS * PROJ;
  short* nv  = nu  + (size_t)NROWS * PROJ;
  short* nus = nv  + (size_t)NROWS * PROJ;
  short* nvs = nus + (size_t)NROWS * PROJ;
  float* dU  = (float*)(nvs + (size_t)NROWS * PROJ);
  float* dV  = dU + NROWS;

  hipMemsetAsync(d_out, 0, sizeof(float), stream);
  hipMemsetAsync(dU, 0, 2 * NROWS * sizeof(float), stream);

  kprep<<<16, 256, 0, stream>>>(W1, W2, W1t, W2t);
  kproj1<<<NROWS / 64, 256, 0, stream>>>(z1, W1t, b1, hb);
  kproj2<<<NROWS / 64, 256, 0, stream>>>(hb, W2t, b2, nu, nus);
  kproj1<<<NROWS / 64, 256, 0, stream>>>(z2, W1t, b1, hb);
  kproj2<<<NROWS / 64, 256, 0, stream>>>(hb, W2t, b2, nv, nvs);
  ksim<<<512, 256, 0, stream>>>(nu, nv, nus, nvs, dU, dV);
  kfinal<<<NROWS / 256, 256, 0, stream>>>(nu, nv, dU, dV, out);
}

// Round 2
// 401.841 us; speedup vs baseline: 1.4026x; 1.4026x over previous
//
#include <hip/hip_runtime.h>

#define NROWS 16384
#define M2    32768   // 2N stacked
#define TT    128     // number of 256-row strips of the stacked matrix
#define HID   512
#define PROJ  128

constexpr float SCALE_L2E = 2.8853900817779268f; // log2(e)/tau, tau=0.5
constexpr float E2        = 7.38905609893065f;   // exp(1/tau) = diag term

typedef float f32x4  __attribute__((ext_vector_type(4)));
typedef short bf16x8 __attribute__((ext_vector_type(8)));

__device__ inline short f2bf(float x) {
  union { float f; unsigned u; } v; v.f = x;
  unsigned r = v.u + 0x7fffu + ((v.u >> 16) & 1u); // RNE
  return (short)(r >> 16);
}
__device__ inline float bf2f(short s) {
  union { unsigned u; float f; } v; v.u = ((unsigned)(unsigned short)s) << 16;
  return v.f;
}

// ---- prep: W1 (512x128) -> W1t bf16 (128x512); W2 (128x128) -> W2t bf16 (128x128)
__global__ void kprep(const float* __restrict__ W1, const float* __restrict__ W2,
                      short* __restrict__ W1t, short* __restrict__ W2t) {
  int stride = gridDim.x * blockDim.x;
  for (int idx = blockIdx.x * blockDim.x + threadIdx.x; idx < 128 * 512; idx += stride) {
    int n = idx >> 9, k = idx & 511;
    W1t[idx] = f2bf(W1[k * 128 + n]);
  }
  for (int idx = blockIdx.x * blockDim.x + threadIdx.x; idx < 128 * 128; idx += stride) {
    int n = idx >> 7, k = idx & 127;
    W2t[idx] = f2bf(W2[k * 128 + n]);
  }
}

// ---- GEMM1: h = elu(z @ W1 + b1), z f32 [16384][512], out bf16 [16384][128]
__global__ __launch_bounds__(256) void kproj1(const float* __restrict__ z,
                                              const short* __restrict__ W1t,
                                              const float* __restrict__ b1,
                                              short* __restrict__ h) {
  int wave = threadIdx.x >> 6, lane = threadIdx.x & 63;
  int lr = lane & 15, lg = lane >> 4;
  int row0 = blockIdx.x * 64 + wave * 16;
  const float* zrow = z + (size_t)(row0 + lr) * HID;

  f32x4 acc[8];
#pragma unroll
  for (int ct = 0; ct < 8; ++ct) acc[ct] = (f32x4){0.f, 0.f, 0.f, 0.f};

  for (int kc = 0; kc < HID / 32; ++kc) {
    int kof = kc * 32 + lg * 8;
    f32x4 za = *(const f32x4*)(zrow + kof);
    f32x4 zb = *(const f32x4*)(zrow + kof + 4);
    bf16x8 a;
    a[0] = f2bf(za[0]); a[1] = f2bf(za[1]); a[2] = f2bf(za[2]); a[3] = f2bf(za[3]);
    a[4] = f2bf(zb[0]); a[5] = f2bf(zb[1]); a[6] = f2bf(zb[2]); a[7] = f2bf(zb[3]);
#pragma unroll
    for (int ct = 0; ct < 8; ++ct) {
      bf16x8 b = *(const bf16x8*)(W1t + (ct * 16 + lr) * HID + kof);
      acc[ct] = __builtin_amdgcn_mfma_f32_16x16x32_bf16(a, b, acc[ct], 0, 0, 0);
    }
  }
  // C/D: col = lane&15, row = (lane>>4)*4 + q
#pragma unroll
  for (int ct = 0; ct < 8; ++ct) {
    int col = ct * 16 + lr;
    float bias = b1[col];
#pragma unroll
    for (int q = 0; q < 4; ++q) {
      int row = row0 + lg * 4 + q;
      float x = acc[ct][q] + bias;
      x = x > 0.f ? x : expm1f(x);
      h[(size_t)row * PROJ + col] = f2bf(x);
    }
  }
}

// ---- GEMM2 + bias + L2-normalize; writes nn (bf16) and ns (bf16 * log2e/tau)
__global__ __launch_bounds__(256) void kproj2(const short* __restrict__ h,
                                              const short* __restrict__ W2t,
                                              const float* __restrict__ b2,
                                              short* __restrict__ outn,
                                              short* __restrict__ outns) {
  int wave = threadIdx.x >> 6, lane = threadIdx.x & 63;
  int lr = lane & 15, lg = lane >> 4;
  int row0 = blockIdx.x * 64 + wave * 16;
  const short* hrow = h + (size_t)(row0 + lr) * PROJ;

  f32x4 acc[8];
#pragma unroll
  for (int ct = 0; ct < 8; ++ct) acc[ct] = (f32x4){0.f, 0.f, 0.f, 0.f};

#pragma unroll
  for (int kc = 0; kc < PROJ / 32; ++kc) {
    int kof = kc * 32 + lg * 8;
    bf16x8 a = *(const bf16x8*)(hrow + kof);
#pragma unroll
    for (int ct = 0; ct < 8; ++ct) {
      bf16x8 b = *(const bf16x8*)(W2t + (ct * 16 + lr) * PROJ + kof);
      acc[ct] = __builtin_amdgcn_mfma_f32_16x16x32_bf16(a, b, acc[ct], 0, 0, 0);
    }
  }
#pragma unroll
  for (int ct = 0; ct < 8; ++ct) {
    float bias = b2[ct * 16 + lr];
#pragma unroll
    for (int q = 0; q < 4; ++q) acc[ct][q] += bias;
  }
  float inv[4];
#pragma unroll
  for (int q = 0; q < 4; ++q) {
    float s = 0.f;
#pragma unroll
    for (int ct = 0; ct < 8; ++ct) s += acc[ct][q] * acc[ct][q];
    s += __shfl_xor(s, 1); s += __shfl_xor(s, 2);
    s += __shfl_xor(s, 4); s += __shfl_xor(s, 8);
    inv[q] = 1.f / fmaxf(sqrtf(s), 1e-12f);
  }
#pragma unroll
  for (int ct = 0; ct < 8; ++ct) {
    int col = ct * 16 + lr;
#pragma unroll
    for (int q = 0; q < 4; ++q) {
      int row = row0 + lg * 4 + q;
      float v = acc[ct][q] * inv[q];
      outn[(size_t)row * PROJ + col]  = f2bf(v);
      outns[(size_t)row * PROJ + col] = f2bf(v * SCALE_L2E);
    }
  }
}

// ---- symmetric similarity: G = Ws @ W^T (stacked 32768x128), upper-triangle
// 256x256 tiles. Off-diag tile (ib<jb): rowsums of exp2(G) -> d[i], colsums -> d[j].
// Diagonal tile: full tile, rowsums only.
__global__ __launch_bounds__(256, 2) void ksim2(const short* __restrict__ nn,
                                                const short* __restrict__ ns,
                                                float* __restrict__ d) {
  int wave = threadIdx.x >> 6, lane = threadIdx.x & 63;
  int lr = lane & 15, lg = lane >> 4;

  // triangular decode: strip ib has TT-ib tiles (jb = ib..TT-1); off(x)=x*(2*TT-x+1)/2
  int t = blockIdx.x;
  float ff = (float)((2 * TT + 1) * (2 * TT + 1) - 8 * t);
  int ib = (int)(((float)(2 * TT + 1) - sqrtf(ff)) * 0.5f);
  if (ib < 0) ib = 0;
  if (ib > TT - 1) ib = TT - 1;
  while (ib > 0 && ib * (2 * TT - ib + 1) / 2 > t) --ib;
  while ((ib + 1) * (2 * TT - ib) / 2 <= t) ++ib;
  int jb = ib + (t - ib * (2 * TT - ib + 1) / 2);
  bool diag = (ib == jb);

  int i0 = ib * 256 + wave * 64;

  // A-fragments: 64 i-rows, scaled matrix. Pin in VGPRs (64 regs).
  bf16x8 a[4][4];
#pragma unroll
  for (int rb = 0; rb < 4; ++rb)
#pragma unroll
    for (int kc = 0; kc < 4; ++kc) {
      a[rb][kc] = *(const bf16x8*)(ns + (size_t)(i0 + rb * 16 + lr) * PROJ + kc * 32 + lg * 8);
      asm volatile("" : "+v"(a[rb][kc]));   // forbid remat/sink into the loop
    }

  float rs[4][4];
#pragma unroll
  for (int rb = 0; rb < 4; ++rb)
#pragma unroll
    for (int q = 0; q < 4; ++q) rs[rb][q] = 0.f;

  const short* pb = nn + (size_t)(jb * 256 + lr) * PROJ + lg * 8;
  for (int jt = 0; jt < 16; ++jt) {
    bf16x8 b[4];
#pragma unroll
    for (int kc = 0; kc < 4; ++kc) b[kc] = *(const bf16x8*)(pb + kc * 32);
    pb += 16 * PROJ;

    float cs = 0.f;
#pragma unroll
    for (int rb = 0; rb < 4; ++rb) {
      f32x4 c = (f32x4){0.f, 0.f, 0.f, 0.f};
#pragma unroll
      for (int kc = 0; kc < 4; ++kc)
        c = __builtin_amdgcn_mfma_f32_16x16x32_bf16(a[rb][kc], b[kc], c, 0, 0, 0);
#pragma unroll
      for (int q = 0; q < 4; ++q) {
        float e = __builtin_amdgcn_exp2f(c[q]);
        rs[rb][q] += e;
        cs += e;
      }
    }
    // column sums: cs holds 16 rows' worth for col (lane&15); fold lane-groups
    cs += __shfl_xor(cs, 16);
    cs += __shfl_xor(cs, 32);
    if (!diag && lg == 0)
      atomicAdd(&d[jb * 256 + jt * 16 + lr], cs);
  }

  // row sums: reduce over the 16 lr-lanes, then one atomic per row (64 lanes <-> 64 rows)
  float myval = 0.f;
#pragma unroll
  for (int rb = 0; rb < 4; ++rb)
#pragma unroll
    for (int q = 0; q < 4; ++q) {
      float v = rs[rb][q];
      v += __shfl_xor(v, 1); v += __shfl_xor(v, 2);
      v += __shfl_xor(v, 4); v += __shfl_xor(v, 8);
      if (lr == rb * 4 + q) myval = v;
    }
  atomicAdd(&d[i0 + (lr >> 2) * 16 + lg * 4 + (lr & 3)], myval);
}

// ---- final: per-row loss, mean into d_out
__global__ __launch_bounds__(256) void kfinal(const short* __restrict__ nn,
                                              const float* __restrict__ d,
                                              float* __restrict__ out) {
  int wave = threadIdx.x >> 6, lane = threadIdx.x & 63;
  int i = blockIdx.x * 256 + threadIdx.x;

  const bf16x8* a = (const bf16x8*)(nn + (size_t)i * PROJ);
  const bf16x8* b = (const bf16x8*)(nn + (size_t)(NROWS + i) * PROJ);
  float s = 0.f;
#pragma unroll
  for (int t = 0; t < PROJ / 8; ++t) {
    bf16x8 x = a[t], y = b[t];
#pragma unroll
    for (int e = 0; e < 8; ++e) s += bf2f(x[e]) * bf2f(y[e]);
  }
  float den1 = d[i] - E2;
  float den2 = d[NROWS + i] - E2;
  // 0.5*(l1+l2) = 0.5*(log den1 + log den2) - s/tau
  float li = 0.5f * (logf(den1) + logf(den2)) - s * 2.0f;

#pragma unroll
  for (int m = 1; m < 64; m <<= 1) li += __shfl_xor(li, m);
  __shared__ float ws4[4];
  if (lane == 0) ws4[wave] = li;
  __syncthreads();
  if (threadIdx.x == 0)
    atomicAdd(out, (ws4[0] + ws4[1] + ws4[2] + ws4[3]) * (1.f / (float)NROWS));
}

extern "C" void kernel_launch(void* const* d_in, const int* in_sizes, int n_in,
                              void* d_out, int out_size, void* d_ws, size_t ws_size,
                              hipStream_t stream) {
  (void)in_sizes; (void)n_in; (void)out_size; (void)ws_size;
  const float* z1 = (const float*)d_in[0];
  const float* z2 = (const float*)d_in[1];
  const float* W1 = (const float*)d_in[2];
  const float* b1 = (const float*)d_in[3];
  const float* W2 = (const float*)d_in[4];
  const float* b2 = (const float*)d_in[5];
  float* out = (float*)d_out;

  short* W1t = (short*)d_ws;                       // 128*512
  short* W2t = W1t + 128 * 512;                    // 128*128
  short* hb  = W2t + 128 * 128;                    // 16384*128
  short* nn  = hb  + (size_t)NROWS * PROJ;         // 32768*128 stacked [u;v] normalized
  short* ns  = nn  + (size_t)M2 * PROJ;            // 32768*128 stacked scaled
  float* d   = (float*)(ns + (size_t)M2 * PROJ);   // 32768 row sums

  hipMemsetAsync(d_out, 0, sizeof(float), stream);
  hipMemsetAsync(d, 0, (size_t)M2 * sizeof(float), stream);

  kprep<<<16, 256, 0, stream>>>(W1, W2, W1t, W2t);
  kproj1<<<NROWS / 64, 256, 0, stream>>>(z1, W1t, b1, hb);
  kproj2<<<NROWS / 64, 256, 0, stream>>>(hb, W2t, b2, nn, ns);
  kproj1<<<NROWS / 64, 256, 0, stream>>>(z2, W1t, b1, hb);
  kproj2<<<NROWS / 64, 256, 0, stream>>>(hb, W2t, b2, nn + (size_t)NROWS * PROJ,
                                         ns + (size_t)NROWS * PROJ);
  ksim2<<<TT * (TT + 1) / 2, 256, 0, stream>>>(nn, ns, d);
  kfinal<<<NROWS / 256, 256, 0, stream>>>(nn, d, out);
}

// Round 3
// 261.527 us; speedup vs baseline: 2.1551x; 1.5365x over previous
//
#include <hip/hip_runtime.h>

#define NROWS 16384
#define M2    32768   // 2N stacked
#define TT    128     // number of 256-row strips of the stacked matrix
#define HID   512
#define PROJ  128

constexpr float SCALE_L2E = 2.8853900817779268f; // log2(e)/tau, tau=0.5
constexpr float E2        = 7.38905609893065f;   // exp(1/tau) = diag term

typedef float f32x4  __attribute__((ext_vector_type(4)));
typedef short bf16x8 __attribute__((ext_vector_type(8)));

__device__ inline short f2bf(float x) {
  union { float f; unsigned u; } v; v.f = x;
  unsigned r = v.u + 0x7fffu + ((v.u >> 16) & 1u); // RNE
  return (short)(r >> 16);
}
__device__ inline float bf2f(short s) {
  union { unsigned u; float f; } v; v.u = ((unsigned)(unsigned short)s) << 16;
  return v.f;
}

// ---- prep: W1 (512x128) -> W1t bf16 (128x512); W2 (128x128) -> W2t bf16 (128x128)
__global__ void kprep(const float* __restrict__ W1, const float* __restrict__ W2,
                      short* __restrict__ W1t, short* __restrict__ W2t) {
  int stride = gridDim.x * blockDim.x;
  for (int idx = blockIdx.x * blockDim.x + threadIdx.x; idx < 128 * 512; idx += stride) {
    int n = idx >> 9, k = idx & 511;
    W1t[idx] = f2bf(W1[k * 128 + n]);
  }
  for (int idx = blockIdx.x * blockDim.x + threadIdx.x; idx < 128 * 128; idx += stride) {
    int n = idx >> 7, k = idx & 127;
    W2t[idx] = f2bf(W2[k * 128 + n]);
  }
}

// ---- GEMM1: h = elu(z @ W1 + b1), z f32 [16384][512], out bf16 [16384][128]
__global__ __launch_bounds__(256) void kproj1(const float* __restrict__ z,
                                              const short* __restrict__ W1t,
                                              const float* __restrict__ b1,
                                              short* __restrict__ h) {
  int wave = threadIdx.x >> 6, lane = threadIdx.x & 63;
  int lr = lane & 15, lg = lane >> 4;
  int row0 = blockIdx.x * 64 + wave * 16;
  const float* zrow = z + (size_t)(row0 + lr) * HID;

  f32x4 acc[8];
#pragma unroll
  for (int ct = 0; ct < 8; ++ct) acc[ct] = (f32x4){0.f, 0.f, 0.f, 0.f};

  for (int kc = 0; kc < HID / 32; ++kc) {
    int kof = kc * 32 + lg * 8;
    f32x4 za = *(const f32x4*)(zrow + kof);
    f32x4 zb = *(const f32x4*)(zrow + kof + 4);
    bf16x8 a;
    a[0] = f2bf(za[0]); a[1] = f2bf(za[1]); a[2] = f2bf(za[2]); a[3] = f2bf(za[3]);
    a[4] = f2bf(zb[0]); a[5] = f2bf(zb[1]); a[6] = f2bf(zb[2]); a[7] = f2bf(zb[3]);
#pragma unroll
    for (int ct = 0; ct < 8; ++ct) {
      bf16x8 b = *(const bf16x8*)(W1t + (ct * 16 + lr) * HID + kof);
      acc[ct] = __builtin_amdgcn_mfma_f32_16x16x32_bf16(a, b, acc[ct], 0, 0, 0);
    }
  }
  // C/D: col = lane&15, row = (lane>>4)*4 + q
#pragma unroll
  for (int ct = 0; ct < 8; ++ct) {
    int col = ct * 16 + lr;
    float bias = b1[col];
#pragma unroll
    for (int q = 0; q < 4; ++q) {
      int row = row0 + lg * 4 + q;
      float x = acc[ct][q] + bias;
      x = x > 0.f ? x : expm1f(x);
      h[(size_t)row * PROJ + col] = f2bf(x);
    }
  }
}

// ---- GEMM2 + bias + L2-normalize; writes nn (bf16) and ns (bf16 * log2e/tau)
__global__ __launch_bounds__(256) void kproj2(const short* __restrict__ h,
                                              const short* __restrict__ W2t,
                                              const float* __restrict__ b2,
                                              short* __restrict__ outn,
                                              short* __restrict__ outns) {
  int wave = threadIdx.x >> 6, lane = threadIdx.x & 63;
  int lr = lane & 15, lg = lane >> 4;
  int row0 = blockIdx.x * 64 + wave * 16;
  const short* hrow = h + (size_t)(row0 + lr) * PROJ;

  f32x4 acc[8];
#pragma unroll
  for (int ct = 0; ct < 8; ++ct) acc[ct] = (f32x4){0.f, 0.f, 0.f, 0.f};

#pragma unroll
  for (int kc = 0; kc < PROJ / 32; ++kc) {
    int kof = kc * 32 + lg * 8;
    bf16x8 a = *(const bf16x8*)(hrow + kof);
#pragma unroll
    for (int ct = 0; ct < 8; ++ct) {
      bf16x8 b = *(const bf16x8*)(W2t + (ct * 16 + lr) * PROJ + kof);
      acc[ct] = __builtin_amdgcn_mfma_f32_16x16x32_bf16(a, b, acc[ct], 0, 0, 0);
    }
  }
#pragma unroll
  for (int ct = 0; ct < 8; ++ct) {
    float bias = b2[ct * 16 + lr];
#pragma unroll
    for (int q = 0; q < 4; ++q) acc[ct][q] += bias;
  }
  float inv[4];
#pragma unroll
  for (int q = 0; q < 4; ++q) {
    float s = 0.f;
#pragma unroll
    for (int ct = 0; ct < 8; ++ct) s += acc[ct][q] * acc[ct][q];
    s += __shfl_xor(s, 1); s += __shfl_xor(s, 2);
    s += __shfl_xor(s, 4); s += __shfl_xor(s, 8);
    inv[q] = 1.f / fmaxf(sqrtf(s), 1e-12f);
  }
#pragma unroll
  for (int ct = 0; ct < 8; ++ct) {
    int col = ct * 16 + lr;
#pragma unroll
    for (int q = 0; q < 4; ++q) {
      int row = row0 + lg * 4 + q;
      float v = acc[ct][q] * inv[q];
      outn[(size_t)row * PROJ + col]  = f2bf(v);
      outns[(size_t)row * PROJ + col] = f2bf(v * SCALE_L2E);
    }
  }
}

// ---- symmetric similarity, LDS-staged.
// G = (L*What) @ What^T over stacked What (32768x128). Upper-triangle 256x256
// tiles; off-diag: rowsums -> d[i-rows], colsums -> d[j-cols]; diag: rowsums only.
// B-tile (256x128 bf16, 64KB) staged in LDS with slot ^= (row&7) XOR swizzle.
__global__ __launch_bounds__(512, 4) void ksim3(const short* __restrict__ nn,
                                                const short* __restrict__ ns,
                                                float* __restrict__ d) {
  __shared__ short Bt[256 * 128];      // swizzled B tile, 64KB
  __shared__ float colbuf[8][256];     // per-wave colsum partials, 8KB

  int tid = threadIdx.x;
  int w = tid >> 6, lane = tid & 63;
  int lr = lane & 15, lg = lane >> 4;

  // triangular decode: tile t -> (ib, jb), jb >= ib
  int t = blockIdx.x;
  float ff = (float)((2 * TT + 1) * (2 * TT + 1) - 8 * t);
  int ib = (int)(((float)(2 * TT + 1) - sqrtf(ff)) * 0.5f);
  if (ib < 0) ib = 0;
  if (ib > TT - 1) ib = TT - 1;
  while (ib > 0 && ib * (2 * TT - ib + 1) / 2 > t) --ib;
  while ((ib + 1) * (2 * TT - ib) / 2 <= t) ++ib;
  int jb = ib + (t - ib * (2 * TT - ib + 1) / 2);
  bool diag = (ib == jb);

  int i0 = ib * 256 + w * 32;

  // A-fragments: this wave's 32 rows of the scaled matrix (32 VGPRs)
  bf16x8 a[2][4];
#pragma unroll
  for (int rb = 0; rb < 2; ++rb)
#pragma unroll
    for (int kc = 0; kc < 4; ++kc)
      a[rb][kc] = *(const bf16x8*)(ns + (size_t)(i0 + rb * 16 + lr) * PROJ + kc * 32 + lg * 8);

  // stage B tile into LDS, swizzled: LDS(row, slot) holds global(row, slot^(row&7))
  {
    int rslot = tid & 15;        // 16B chunk within a row
    int rrow0 = tid >> 4;        // 0..31
    bf16x8 st[8];
    const short* bsrc = nn + (size_t)jb * 256 * PROJ + (size_t)rrow0 * PROJ + rslot * 8;
#pragma unroll
    for (int r = 0; r < 8; ++r) st[r] = *(const bf16x8*)(bsrc + (size_t)r * 32 * PROJ);
#pragma unroll
    for (int r = 0; r < 8; ++r) {
      int row = r * 32 + rrow0;
      int sl = rslot ^ (row & 7);
      *(bf16x8*)((char*)Bt + row * 256 + sl * 16) = st[r];
    }
  }
  __syncthreads();

  float rs[2][4];
#pragma unroll
  for (int rb = 0; rb < 2; ++rb)
#pragma unroll
    for (int q = 0; q < 4; ++q) rs[rb][q] = 0.f;

  const char* bbase = (const char*)Bt + lr * 256;  // row = jt*16+lr; row&7 == lr&7
  int sx = lr & 7;

#pragma unroll 4
  for (int jt = 0; jt < 16; ++jt) {
    bf16x8 b[4];
#pragma unroll
    for (int kc = 0; kc < 4; ++kc)
      b[kc] = *(const bf16x8*)(bbase + jt * 4096 + (((kc * 4 + lg) ^ sx) << 4));

    float cs = 0.f;
#pragma unroll
    for (int rb = 0; rb < 2; ++rb) {
      f32x4 c = (f32x4){0.f, 0.f, 0.f, 0.f};
#pragma unroll
      for (int kc = 0; kc < 4; ++kc)
        c = __builtin_amdgcn_mfma_f32_16x16x32_bf16(a[rb][kc], b[kc], c, 0, 0, 0);
#pragma unroll
      for (int q = 0; q < 4; ++q) {
        float e = __builtin_amdgcn_exp2f(c[q]);
        rs[rb][q] += e;
        cs += e;
      }
    }
    // colsum partial for col jt*16+lr over this wave's 32 rows
    cs += __shfl_xor(cs, 16);
    cs += __shfl_xor(cs, 32);
    if (lg == 0) colbuf[w][jt * 16 + lr] = cs;
  }

  // rowsums: reduce over the 16 lr lanes, one atomic instruction per wave
  float myval = 0.f;
#pragma unroll
  for (int rb = 0; rb < 2; ++rb)
#pragma unroll
    for (int q = 0; q < 4; ++q) {
      float v = rs[rb][q];
      v += __shfl_xor(v, 1); v += __shfl_xor(v, 2);
      v += __shfl_xor(v, 4); v += __shfl_xor(v, 8);
      if (lr == rb * 4 + q) myval = v;
    }
  if (lr < 8)
    atomicAdd(&d[i0 + (lr >> 2) * 16 + lg * 4 + (lr & 3)], myval);

  // colsums: cross-wave reduce in LDS, then one atomic per column
  __syncthreads();
  if (!diag && tid < 256) {
    float s = 0.f;
#pragma unroll
    for (int w2 = 0; w2 < 8; ++w2) s += colbuf[w2][tid];
    atomicAdd(&d[jb * 256 + tid], s);
  }
}

// ---- final: per-row loss, mean into d_out
__global__ __launch_bounds__(256) void kfinal(const short* __restrict__ nn,
                                              const float* __restrict__ d,
                                              float* __restrict__ out) {
  int wave = threadIdx.x >> 6, lane = threadIdx.x & 63;
  int i = blockIdx.x * 256 + threadIdx.x;

  const bf16x8* a = (const bf16x8*)(nn + (size_t)i * PROJ);
  const bf16x8* b = (const bf16x8*)(nn + (size_t)(NROWS + i) * PROJ);
  float s = 0.f;
#pragma unroll
  for (int t = 0; t < PROJ / 8; ++t) {
    bf16x8 x = a[t], y = b[t];
#pragma unroll
    for (int e = 0; e < 8; ++e) s += bf2f(x[e]) * bf2f(y[e]);
  }
  float den1 = d[i] - E2;
  float den2 = d[NROWS + i] - E2;
  // 0.5*(l1+l2) = 0.5*(log den1 + log den2) - s/tau
  float li = 0.5f * (logf(den1) + logf(den2)) - s * 2.0f;

#pragma unroll
  for (int m = 1; m < 64; m <<= 1) li += __shfl_xor(li, m);
  __shared__ float ws4[4];
  if (lane == 0) ws4[wave] = li;
  __syncthreads();
  if (threadIdx.x == 0)
    atomicAdd(out, (ws4[0] + ws4[1] + ws4[2] + ws4[3]) * (1.f / (float)NROWS));
}

extern "C" void kernel_launch(void* const* d_in, const int* in_sizes, int n_in,
                              void* d_out, int out_size, void* d_ws, size_t ws_size,
                              hipStream_t stream) {
  (void)in_sizes; (void)n_in; (void)out_size; (void)ws_size;
  const float* z1 = (const float*)d_in[0];
  const float* z2 = (const float*)d_in[1];
  const float* W1 = (const float*)d_in[2];
  const float* b1 = (const float*)d_in[3];
  const float* W2 = (const float*)d_in[4];
  const float* b2 = (const float*)d_in[5];
  float* out = (float*)d_out;

  short* W1t = (short*)d_ws;                       // 128*512
  short* W2t = W1t + 128 * 512;                    // 128*128
  short* hb  = W2t + 128 * 128;                    // 16384*128
  short* nn  = hb  + (size_t)NROWS * PROJ;         // 32768*128 stacked [u;v] normalized
  short* ns  = nn  + (size_t)M2 * PROJ;            // 32768*128 stacked scaled
  float* d   = (float*)(ns + (size_t)M2 * PROJ);   // 32768 row sums

  hipMemsetAsync(d_out, 0, sizeof(float), stream);
  hipMemsetAsync(d, 0, (size_t)M2 * sizeof(float), stream);

  kprep<<<16, 256, 0, stream>>>(W1, W2, W1t, W2t);
  kproj1<<<NROWS / 64, 256, 0, stream>>>(z1, W1t, b1, hb);
  kproj2<<<NROWS / 64, 256, 0, stream>>>(hb, W2t, b2, nn, ns);
  kproj1<<<NROWS / 64, 256, 0, stream>>>(z2, W1t, b1, hb);
  kproj2<<<NROWS / 64, 256, 0, stream>>>(hb, W2t, b2, nn + (size_t)NROWS * PROJ,
                                         ns + (size_t)NROWS * PROJ);
  ksim3<<<TT * (TT + 1) / 2, 512, 0, stream>>>(nn, ns, d);
  kfinal<<<NROWS / 256, 256, 0, stream>>>(nn, d, out);
}